// Round 2
// baseline (384.811 us; speedup 1.0000x reference)
//
#include <hip/hip_runtime.h>

// Problem constants (fixed by the reference: x,y are (3000, 800, 8) f32)
#define NT   3000          // time samples per trace
#define NK   2999          // NT-1 (cdf length)
#define NTR  6400          // number of traces (800*8); trace n element t at X[t*NTR+n]
#define CCH  32            // time chunks per trace
#define KCH  94            // ceil(NK/CCH); last chunk has 85
#define BLK  256

// sum_{i=1..2999} i  (weight for folding mind into S = sum of cdf)
#define TRIW 4498500.0f

// ---------------------------------------------------------------------------
// Kernel A: per (trace n, chunk c) compute raw chunk statistics:
//   cmn  = min over a[t], t in [j0 .. j1]   (covers all t across chunks)
//   ss*  = sum_{j in chunk} s_raw[j]                (for cdf chunk offsets)
//   ws*  = sum_{j in chunk} s_raw[j]*(NK - j)       (for S = sum of cdf)
// where s_raw[j] = 0.5*(a[j]+a[j+1]).
// Layout of outputs: [c*NTR + n]  (coalesced for both writer and reader).
// ---------------------------------------------------------------------------
__global__ __launch_bounds__(BLK) void kA(
    const float* __restrict__ X, const float* __restrict__ Y,
    float* __restrict__ ssx, float* __restrict__ ssy,
    float* __restrict__ wsx, float* __restrict__ wsy,
    float* __restrict__ cmn)
{
    const int n = blockIdx.x * BLK + threadIdx.x;   // trace
    const int c = blockIdx.y;                       // chunk
    const int j0 = c * KCH;
    const int j1 = min(NK, j0 + KCH);

    float xp = X[j0 * NTR + n];
    float yp = Y[j0 * NTR + n];
    float mn = fminf(xp, yp);
    float sxs = 0.f, sys = 0.f, wxs = 0.f, wys = 0.f;

    for (int j = j0; j < j1; ++j) {
        const float xn = X[(j + 1) * NTR + n];
        const float yn = Y[(j + 1) * NTR + n];
        const float sx = 0.5f * (xp + xn);
        const float sy = 0.5f * (yp + yn);
        const float wgt = (float)(NK - j);
        sxs += sx; sys += sy;
        wxs = fmaf(sx, wgt, wxs);
        wys = fmaf(sy, wgt, wys);
        mn = fminf(mn, fminf(xn, yn));
        xp = xn; yp = yn;
    }

    const int o = c * NTR + n;
    ssx[o] = sxs; ssy[o] = sys;
    wsx[o] = wxs; wsy[o] = wys;
    cmn[o] = mn;
}

// ---------------------------------------------------------------------------
// Kernel B: per trace n: reduce min over chunks, exclusive-scan chunk sums
// into cdf offsets, derive S_syn/S_obs (min-shift folded in algebraically).
// Thread 0 zeroes the output accumulator (d_out is poisoned before each call).
// ---------------------------------------------------------------------------
__global__ __launch_bounds__(BLK) void kB(
    const float* __restrict__ ssx, const float* __restrict__ ssy,
    const float* __restrict__ wsx, const float* __restrict__ wsy,
    const float* __restrict__ cmn,
    float* __restrict__ offx, float* __restrict__ offy,
    float* __restrict__ mindA, float* __restrict__ SsynA,
    float* __restrict__ SobsA, float* __restrict__ out)
{
    const int n = blockIdx.x * BLK + threadIdx.x;
    if (blockIdx.x == 0 && threadIdx.x == 0) out[0] = 0.0f;

    float mn = 3.4e38f;
    for (int c = 0; c < CCH; ++c) mn = fminf(mn, cmn[c * NTR + n]);

    float rx = 0.f, ry = 0.f, wx = 0.f, wy = 0.f;
    for (int c = 0; c < CCH; ++c) {
        const int o = c * NTR + n;
        offx[o] = rx; offy[o] = ry;
        rx += ssx[o]; ry += ssy[o];
        wx += wsx[o]; wy += wsy[o];
    }

    mindA[n] = mn;
    SsynA[n] = wx - mn * TRIW;   // S = sum_k cdf'[k]
    SobsA[n] = wy - mn * TRIW;
}

// ---------------------------------------------------------------------------
// Kernel C: per (trace n, k-chunk c): two-pointer merge.
//   syn cursor: k walks [j0, j1), cdf'_syn[k] streamed from X + chunk offset.
//   obs cursor: m initialized via the 32 chunk-boundary cdf values, then
//               advanced while obs'[m] < syn'[k] (cross-multiplied compare).
//   idx[k] = m  (count of obs' strictly < syn'  == searchsorted side='left').
//   acc += (k+1 - m)^2 * cdf'_syn[k] / S_syn.
// Block-reduce acc, one atomicAdd per block.
// ---------------------------------------------------------------------------
__global__ __launch_bounds__(BLK) void kC(
    const float* __restrict__ X, const float* __restrict__ Y,
    const float* __restrict__ offx, const float* __restrict__ offy,
    const float* __restrict__ mindA, const float* __restrict__ SsynA,
    const float* __restrict__ SobsA, float* __restrict__ out)
{
    const int n = blockIdx.x * BLK + threadIdx.x;
    const int c = blockIdx.y;
    const int j0 = c * KCH;
    const int j1 = min(NK, j0 + KCH);

    const float mind = mindA[n];
    const float Ssyn = SsynA[n];
    const float Sobs = SobsA[n];
    const float invS = 1.0f / Ssyn;

    float cs = offx[c * NTR + n];      // raw syn cumsum through j0-1
    float xp = X[j0 * NTR + n];

    int   m  = -1;                     // obs cursor (uninitialized)
    float co = 0.f;                    // raw obs cumsum through m-1
    float yp = 0.f;                    // y[m]
    float acc = 0.f;

    for (int k = j0; k < j1; ++k) {
        const float xn = X[(k + 1) * NTR + n];
        cs += 0.5f * (xp + xn);
        xp = xn;
        const float syn_p  = cs - (float)(k + 1) * mind;  // cdf'_syn[k]
        const float target = syn_p * Sobs;

        if (m < 0) {
            // locate starting obs chunk: largest c2 with cdf'_obs[c2*KCH-1] < syn'[k0]
            int cc = 0;
            for (int c2 = CCH - 1; c2 >= 1; --c2) {
                const float v = (offy[c2 * NTR + n] - (float)(c2 * KCH) * mind) * Ssyn;
                if (v < target) { cc = c2; break; }
            }
            m  = cc * KCH;
            co = offy[cc * NTR + n];
            yp = Y[m * NTR + n];
        }

        while (m < NK) {
            const float yn = Y[(m + 1) * NTR + n];
            const float s  = 0.5f * (yp + yn);
            const float obs_p = co + s - (float)(m + 1) * mind;
            if (obs_p * Ssyn < target) { co += s; yp = yn; ++m; }
            else break;
        }

        const float diff = (float)(k + 1 - m);
        acc = fmaf(diff * diff, syn_p * invS, acc);
    }

    // block reduction -> one atomic per block
    __shared__ float red[BLK];
    red[threadIdx.x] = acc;
    __syncthreads();
    for (int s = BLK / 2; s > 0; s >>= 1) {
        if (threadIdx.x < s) red[threadIdx.x] += red[threadIdx.x + s];
        __syncthreads();
    }
    if (threadIdx.x == 0) atomicAdd(out, red[0]);
}

// ---------------------------------------------------------------------------
extern "C" void kernel_launch(void* const* d_in, const int* in_sizes, int n_in,
                              void* d_out, int out_size, void* d_ws, size_t ws_size,
                              hipStream_t stream)
{
    const float* X = (const float*)d_in[0];
    const float* Y = (const float*)d_in[1];
    float* out = (float*)d_out;

    float* w = (float*)d_ws;
    float* ssx  = w;                  // CCH*NTR
    float* ssy  = ssx  + CCH * NTR;
    float* wsx  = ssy  + CCH * NTR;
    float* wsy  = wsx  + CCH * NTR;
    float* cmn  = wsy  + CCH * NTR;
    float* offx = cmn  + CCH * NTR;
    float* offy = offx + CCH * NTR;
    float* mindA = offy + CCH * NTR;  // NTR
    float* SsynA = mindA + NTR;
    float* SobsA = SsynA + NTR;
    // total: 7*CCH*NTR + 3*NTR floats = 5,811,200 bytes

    dim3 grid2(NTR / BLK, CCH);
    dim3 grid1(NTR / BLK);
    dim3 blk(BLK);

    kA<<<grid2, blk, 0, stream>>>(X, Y, ssx, ssy, wsx, wsy, cmn);
    kB<<<grid1, blk, 0, stream>>>(ssx, ssy, wsx, wsy, cmn,
                                  offx, offy, mindA, SsynA, SobsA, out);
    kC<<<grid2, blk, 0, stream>>>(X, Y, offx, offy, mindA, SsynA, SobsA, out);
}

// Round 3
// 317.814 us; speedup vs baseline: 1.2108x; 1.2108x over previous
//
#include <hip/hip_runtime.h>

// Problem constants (fixed by the reference: x,y are (3000, 800, 8) f32)
#define NT   3000          // time samples per trace
#define NK   2999          // NT-1 (cdf length)
#define NTR  6400          // traces (800*8); trace n element t at X[t*NTR+n]
#define NPAIR 3200         // NTR/2 (float2 trace pairs)
#define CCH  64            // time chunks per trace
#define KCH  47            // ceil(NK/CCH); last chunk has 38
#define GRP  8             // obs register-group size

// sum_{i=1..2999} i (weight for folding mind into S = sum of cdf)
#define TRIW 4498500.0f
#define FINF 3.4e38f

// ---------------------------------------------------------------------------
// Kernel A: per (trace-pair p, chunk c), float2-vectorized:
//   chunk min (joint x,y), chunk sum of s_raw (written to offx/offy; kB scans
//   in-place), and chunk weighted sum s_raw*(NK-j) atomically folded into
//   per-trace accumulators wsxA/wsyA (zeroed by hipMemsetAsync).
// ---------------------------------------------------------------------------
__global__ __launch_bounds__(128) void kA(
    const float* __restrict__ X, const float* __restrict__ Y,
    float* __restrict__ offx, float* __restrict__ offy,
    float* __restrict__ cmn,
    float* __restrict__ wsxA, float* __restrict__ wsyA)
{
    const int p = blockIdx.x * 128 + threadIdx.x;   // pair index 0..3199
    const int n = 2 * p;
    const int c = blockIdx.y;
    const int j0 = c * KCH;
    const int j1 = min(NK, j0 + KCH);

    const float2* __restrict__ X2 = (const float2*)X;
    const float2* __restrict__ Y2 = (const float2*)Y;

    float2 xp = X2[j0 * NPAIR + p];
    float2 yp = Y2[j0 * NPAIR + p];
    float mn0 = fminf(xp.x, yp.x), mn1 = fminf(xp.y, yp.y);
    float sx0 = 0.f, sx1 = 0.f, sy0 = 0.f, sy1 = 0.f;
    float wx0 = 0.f, wx1 = 0.f, wy0 = 0.f, wy1 = 0.f;

    #pragma unroll 4
    for (int j = j0; j < j1; ++j) {
        const float2 xn = X2[(j + 1) * NPAIR + p];
        const float2 yn = Y2[(j + 1) * NPAIR + p];
        const float w = (float)(NK - j);
        float s;
        s = 0.5f * (xp.x + xn.x); sx0 += s; wx0 = fmaf(s, w, wx0);
        s = 0.5f * (xp.y + xn.y); sx1 += s; wx1 = fmaf(s, w, wx1);
        s = 0.5f * (yp.x + yn.x); sy0 += s; wy0 = fmaf(s, w, wy0);
        s = 0.5f * (yp.y + yn.y); sy1 += s; wy1 = fmaf(s, w, wy1);
        mn0 = fminf(mn0, fminf(xn.x, yn.x));
        mn1 = fminf(mn1, fminf(xn.y, yn.y));
        xp = xn; yp = yn;
    }

    const int o = c * NTR + n;
    *(float2*)&offx[o] = make_float2(sx0, sx1);
    *(float2*)&offy[o] = make_float2(sy0, sy1);
    *(float2*)&cmn[o]  = make_float2(mn0, mn1);
    atomicAdd(&wsxA[n], wx0); atomicAdd(&wsxA[n + 1], wx1);
    atomicAdd(&wsyA[n], wy0); atomicAdd(&wsyA[n + 1], wy1);
}

// ---------------------------------------------------------------------------
// Kernel B: per trace: min-reduce, in-place exclusive scan of chunk sums
// (raw cdf offsets), derive S_syn/S_obs. Thread 0 zeroes the accumulator.
// ---------------------------------------------------------------------------
__global__ __launch_bounds__(256) void kB(
    float* __restrict__ offx, float* __restrict__ offy,
    const float* __restrict__ cmn,
    const float* __restrict__ wsxA, const float* __restrict__ wsyA,
    float* __restrict__ mindA, float* __restrict__ SsynA,
    float* __restrict__ SobsA, float* __restrict__ out)
{
    const int n = blockIdx.x * 256 + threadIdx.x;
    if (blockIdx.x == 0 && threadIdx.x == 0) out[0] = 0.0f;

    float mn = FINF;
    for (int c = 0; c < CCH; ++c) mn = fminf(mn, cmn[c * NTR + n]);

    float rx = 0.f, ry = 0.f;
    for (int c = 0; c < CCH; ++c) {
        const int o = c * NTR + n;
        const float tx = offx[o], ty = offy[o];
        offx[o] = rx; offy[o] = ry;
        rx += tx; ry += ty;
    }

    mindA[n] = mn;
    SsynA[n] = wsxA[n] - mn * TRIW;
    SobsA[n] = wsyA[n] - mn * TRIW;
}

// ---------------------------------------------------------------------------
// Kernel C: per (trace n, k-chunk c) merge with register-group obs batching.
// Group invariant: obs indices < mbase all have cdf' < every past target
// (targets are monotone), so idx = mbase + popcount(o[i] < target).
// Refill = 8 INDEPENDENT gathers (breaks the dependent-load chain 8x).
// ---------------------------------------------------------------------------
__global__ __launch_bounds__(256) void kC(
    const float* __restrict__ X, const float* __restrict__ Y,
    const float* __restrict__ offx, const float* __restrict__ offy,
    const float* __restrict__ mindA, const float* __restrict__ SsynA,
    const float* __restrict__ SobsA, float* __restrict__ out)
{
    const int n = blockIdx.x * 256 + threadIdx.x;
    const int c = blockIdx.y;
    const int j0 = c * KCH;
    const int j1 = min(NK, j0 + KCH);

    const float mind = mindA[n];
    const float Ssyn = SsynA[n];
    const float Sobs = SobsA[n];
    const float invS = 1.0f / Ssyn;

    float cs = offx[c * NTR + n];      // raw syn cumsum through j0-1
    float xp = X[j0 * NTR + n];
    float acc = 0.f;

    // obs group state (o[] only touched in fully-unrolled loops -> registers)
    int   mbase;                        // group covers obs idx [mbase, mbase+8)
    float co;                           // raw obs cumsum through mbase-1
    float ylast;                        // y[mbase]
    float o[GRP];
    float co8, y8;                      // raw state after mbase+7 (valid iff full)

    #define FILL() do {                                                   \
        float yl_ = ylast, cc_ = co;                                      \
        _Pragma("unroll")                                                 \
        for (int i = 0; i < GRP; ++i) {                                   \
            const int m_ = mbase + i;                                     \
            const int ml_ = (m_ < NK) ? (m_ + 1) : NK;                    \
            const float yn_ = Y[ml_ * NTR + n];                           \
            cc_ += 0.5f * (yl_ + yn_);                                    \
            yl_ = yn_;                                                    \
            const float v_ = (cc_ - (float)(m_ + 1) * mind) * Ssyn;       \
            o[i] = (m_ < NK) ? v_ : FINF;                                 \
        }                                                                 \
        co8 = cc_; y8 = yl_;                                              \
    } while (0)

    #define COUNT(tgt, cnt) do {                                          \
        cnt = 0;                                                          \
        _Pragma("unroll")                                                 \
        for (int i = 0; i < GRP; ++i) cnt += (o[i] < (tgt)) ? 1 : 0;      \
    } while (0)

    // ---- peel k = j0: locate obs start chunk, init group --------------
    {
        const float xn = X[(j0 + 1) * NTR + n];
        cs += 0.5f * (xp + xn); xp = xn;
        const float synp = cs - (float)(j0 + 1) * mind;
        const float target = synp * Sobs;

        // any boundary with cdf' < target is a valid (conservative) start;
        // scan down from c+2 since idx ~= k statistically.
        int cc = 0;
        for (int c2 = min(CCH - 1, c + 2); c2 >= 1; --c2) {
            const float v = (offy[c2 * NTR + n] - (float)(c2 * KCH) * mind) * Ssyn;
            if (v < target) { cc = c2; break; }
        }
        mbase = cc * KCH;
        co = offy[cc * NTR + n];
        ylast = Y[mbase * NTR + n];
        FILL();
        int cnt; COUNT(target, cnt);
        while (cnt == GRP) {            // o[7] finite -> full group consumed
            mbase += GRP; co = co8; ylast = y8;
            FILL();
            COUNT(target, cnt);
        }
        const float diff = (float)(j0 + 1 - (mbase + cnt));
        acc = fmaf(diff * diff, synp * invS, acc);
    }

    // ---- main merge ---------------------------------------------------
    for (int k = j0 + 1; k < j1; ++k) {
        const float xn = X[(k + 1) * NTR + n];
        cs += 0.5f * (xp + xn); xp = xn;
        const float synp = cs - (float)(k + 1) * mind;
        const float target = synp * Sobs;

        int cnt; COUNT(target, cnt);
        while (cnt == GRP) {
            mbase += GRP; co = co8; ylast = y8;
            FILL();
            COUNT(target, cnt);
        }
        const float diff = (float)(k + 1 - (mbase + cnt));
        acc = fmaf(diff * diff, synp * invS, acc);
    }

    #undef FILL
    #undef COUNT

    // block reduction -> one atomic per block
    __shared__ float red[256];
    red[threadIdx.x] = acc;
    __syncthreads();
    for (int s = 128; s > 0; s >>= 1) {
        if (threadIdx.x < s) red[threadIdx.x] += red[threadIdx.x + s];
        __syncthreads();
    }
    if (threadIdx.x == 0) atomicAdd(out, red[0]);
}

// ---------------------------------------------------------------------------
extern "C" void kernel_launch(void* const* d_in, const int* in_sizes, int n_in,
                              void* d_out, int out_size, void* d_ws, size_t ws_size,
                              hipStream_t stream)
{
    const float* X = (const float*)d_in[0];
    const float* Y = (const float*)d_in[1];
    float* out = (float*)d_out;

    float* w = (float*)d_ws;
    float* offx  = w;                    // CCH*NTR
    float* offy  = offx + CCH * NTR;     // CCH*NTR
    float* cmn   = offy + CCH * NTR;     // CCH*NTR
    float* wsxA  = cmn  + CCH * NTR;     // NTR
    float* wsyA  = wsxA + NTR;           // NTR
    float* mindA = wsyA + NTR;           // NTR
    float* SsynA = mindA + NTR;          // NTR
    float* SobsA = SsynA + NTR;          // NTR
    // total: 3*CCH*NTR + 5*NTR floats = 5,043,200 bytes

    hipMemsetAsync(wsxA, 0, 2 * NTR * sizeof(float), stream);

    dim3 gA(NPAIR / 128, CCH), bA(128);
    dim3 gB(NTR / 256), bB(256);
    dim3 gC(NTR / 256, CCH), bC(256);

    kA<<<gA, bA, 0, stream>>>(X, Y, offx, offy, cmn, wsxA, wsyA);
    kB<<<gB, bB, 0, stream>>>(offx, offy, cmn, wsxA, wsyA,
                              mindA, SsynA, SobsA, out);
    kC<<<gC, bC, 0, stream>>>(X, Y, offx, offy, mindA, SsynA, SobsA, out);
}